// Round 15
// baseline (39.674 us; speedup 1.0000x reference)
//
#include <hip/hip_runtime.h>
#include <hip/hip_bf16.h>
#include <stdint.h>

typedef __bf16 bf16_t;
typedef bf16_t bf16x8 __attribute__((ext_vector_type(8)));
typedef bf16_t bf16x4 __attribute__((ext_vector_type(4)));
typedef bf16_t bf16x2 __attribute__((ext_vector_type(2)));
typedef float f32x4 __attribute__((ext_vector_type(4)));
typedef float f32x16 __attribute__((ext_vector_type(16)));
typedef uint32_t u32x4 __attribute__((ext_vector_type(4)));
typedef int   i32x4 __attribute__((ext_vector_type(4)));

#define BB 2
#define SQ 2048
#define SK 2048
#define NH 16
#define HKV 4
#define DD 64
#define GQ 4
#define MTILE 128           // q rows per block (32 per wave, 4 waves)
#define NTILE 64
#define MAXNT 32

#define KTILE_BYTES 8192
#define CNT_OFF   ((size_t)0)
#define KC_OFF    ((size_t)4096)
#define VC_OFF    (KC_OFF + (size_t)BB * HKV * MAXNT * KTILE_BYTES)   // +2MB

// 128B rows, XOR swizzle at 8B granularity (R8-verified conflict-free).
__device__ __forceinline__ int swz8(int row, int colByte) {
    return row * 128 + (colByte ^ ((row & 15) << 3));
}

#define GLDS(g, l) __builtin_amdgcn_global_load_lds( \
    (const __attribute__((address_space(1))) void*)(g), \
    (__attribute__((address_space(3))) void*)(l), 16, 0, 0)

// ------------- pass 1: scan(mask) + gather + f32->bf16 + bake swizzle --------
// R15: grid doubled to 512 blocks (half-tile each, 32 s-rows) — gather was
// latency-bound at 1 block/CU; halving per-thread gathered-load chains and
// doubling TLP attacks that. Mask rescan stays per-block (parallel redundancy
// beat the serial scan stage, R12: +4.2 µs).
__global__ __launch_bounds__(256)
void gather_kernel(const float* __restrict__ kv, const int* __restrict__ mask,
                   char* __restrict__ ws)
{
    __shared__ int wtot[4];
    __shared__ int cwin[32];

    const int bid  = blockIdx.x;           // [b][hk][tile][half]
    const int h2   = bid & 1;
    const int tile = (bid >> 1) & 31;
    const int bh   = bid >> 6;
    const int hk   = bh & 3;
    const int b    = bh >> 2;
    const int tid  = threadIdx.x;
    const int lane = tid & 63;
    const int wid  = tid >> 6;

    int m[8], c = 0;
    {
        const int base = b * SK + tid * 8;
        i32x4 a0 = *(const i32x4*)&mask[base];
        i32x4 a1 = *(const i32x4*)&mask[base + 4];
        #pragma unroll
        for (int j = 0; j < 4; ++j) { m[j] = a0[j] ? 1 : 0; c += m[j]; }
        #pragma unroll
        for (int j = 0; j < 4; ++j) { m[4 + j] = a1[j] ? 1 : 0; c += m[4 + j]; }
    }
    int sc = c;
    #pragma unroll
    for (int off = 1; off < 64; off <<= 1) {
        int n = __shfl_up(sc, off, 64);
        if (lane >= off) sc += n;
    }
    if (lane == 63) wtot[wid] = sc;
    __syncthreads();
    int wbase = 0;
    #pragma unroll
    for (int w = 0; w < 4; ++w) if (w < wid) wbase += wtot[w];
    const int cnt = wtot[0] + wtot[1] + wtot[2] + wtot[3];

    if (hk == 0 && tile == 0 && h2 == 0 && tid == 0)
        ((int*)(ws + CNT_OFF))[b] = cnt;

    const int w0 = tile * NTILE + h2 * 32;   // this block's 32-slot window
    int pos = wbase + sc - c;                // exclusive prefix
    #pragma unroll
    for (int j = 0; j < 8; ++j)
        if (m[j]) {
            if (pos >= w0 && pos < w0 + 32) cwin[pos - w0] = tid * 8 + j;
            ++pos;
        }
    __syncthreads();

    const int nt = (cnt + 63) >> 6;
    if (tile >= nt) return;

    const int s2 = tid >> 4;               // 0..15 (pair-of-rows group)
    const int d0 = (tid & 15) * 4;         // 0..60

    const int tb = (b * HKV + hk) * MAXNT + tile;
    bf16_t* Kt = (bf16_t*)(ws + KC_OFF + (size_t)tb * KTILE_BYTES);
    bf16_t* Vt = (bf16_t*)(ws + VC_OFF + (size_t)tb * KTILE_BYTES);

    f32x4 kk4[2], vv4[2];
    #pragma unroll
    for (int p = 0; p < 2; ++p) {
        const int crow = w0 + s2 * 2 + p;
        if (crow < cnt) {
            const int s = cwin[s2 * 2 + p];
            const float* base = kv + (size_t)((b * SK + s) * 2) * (HKV * DD) + hk * DD + d0;
            kk4[p] = *(const f32x4*)base;
            vv4[p] = *(const f32x4*)(base + HKV * DD);
        } else {
            kk4[p] = (f32x4)(0.f);
            vv4[p] = (f32x4)(0.f);
        }
    }
    #pragma unroll
    for (int p = 0; p < 2; ++p) {
        const int r = h2 * 32 + s2 * 2 + p;    // full-tile row
        bf16x4 kb;
        #pragma unroll
        for (int j = 0; j < 4; ++j) kb[j] = (bf16_t)kk4[p][j];
        *(bf16x4*)((char*)Kt + swz8(r, d0 * 2)) = kb;
    }
    #pragma unroll
    for (int j = 0; j < 4; ++j) {
        bf16x2 tv;
        #pragma unroll
        for (int p = 0; p < 2; ++p) tv[p] = (bf16_t)vv4[p][j];
        // V^T row d0+j, cols s = h2*32 + s2*2 (+p); 4B write, 4B-aligned
        *(bf16x2*)((char*)Vt + swz8(d0 + j, (h2 * 32 + s2 * 2) * 2)) = tv;
    }
}

// ------------- pass 2: pair-pipelined flash attn (R14 verbatim) --------------
__global__ __launch_bounds__(256, 2)
void fattn32p(const float* __restrict__ q, const char* __restrict__ ws,
              float* __restrict__ out)
{
    __shared__ __align__(16) bf16_t Ks[4][NTILE * 64];   // 32 KB
    __shared__ __align__(16) bf16_t Vs[4][DD * 64];      // 32 KB

    const int tid  = threadIdx.x;
    const int wid  = tid >> 6;
    const int lane = tid & 63;
    const int l31  = lane & 31;
    const int hf   = lane >> 5;

    // XCD-aware swizzle: 512 wgs, 8 XCDs, 64-wg chunks
    const int bid = (blockIdx.x & 7) * 64 + (blockIdx.x >> 3);
    const int qt  = bid & 15;
    const int bh  = bid >> 4;
    const int hq  = bh & 15;
    const int b   = bh >> 4;
    const int hk  = hq / GQ;

    const int cnt = ((const int*)(ws + CNT_OFF))[b];
    const int nt  = (cnt + 63) >> 6;

    const int qrow0 = qt * MTILE + wid * 32;
    const float SC = 0.18033688011112042f;   // 0.125 * log2(e)

    bf16x8 qf[4];
    {
        const float* qp = q + ((size_t)(b * SQ + qrow0 + l31) * NH + hq) * DD;
        #pragma unroll
        for (int kblk = 0; kblk < 4; ++kblk) {
            f32x4 v0 = *(const f32x4*)(qp + kblk * 16 + hf * 8);
            f32x4 v1 = *(const f32x4*)(qp + kblk * 16 + hf * 8 + 4);
            #pragma unroll
            for (int j = 0; j < 4; ++j) {
                qf[kblk][j]     = (bf16_t)(v0[j] * SC);
                qf[kblk][4 + j] = (bf16_t)(v1[j] * SC);
            }
        }
    }

    const char* kgb = ws + KC_OFF + (size_t)((b * HKV + hk) * MAXNT) * KTILE_BYTES;
    const char* vgb = ws + VC_OFF + (size_t)((b * HKV + hk) * MAXNT) * KTILE_BYTES;

    auto STAGE = [&](int t, int buf) {
        const char* ksrc = kgb + (size_t)t * KTILE_BYTES + wid * 2048 + lane * 16;
        const char* vsrc = vgb + (size_t)t * KTILE_BYTES + wid * 2048 + lane * 16;
        char* kdst = (char*)Ks[buf] + wid * 2048;
        char* vdst = (char*)Vs[buf] + wid * 2048;
        GLDS(ksrc, kdst);
        GLDS(ksrc + 1024, kdst + 1024);
        GLDS(vsrc, vdst);
        GLDS(vsrc + 1024, vdst + 1024);
    };

    // paired-b64 swizzled fragment read (bank-minimal, verified R8)
    auto LD8 = [&](const bf16_t* T, int row, int cB) -> bf16x8 {
        const char* p = (const char*)T + row * 128;
        const int x = (row & 15) << 3;
        union { bf16x4 h[2]; bf16x8 v; } u;
        u.h[0] = *(const bf16x4*)(p + (cB ^ x));
        u.h[1] = *(const bf16x4*)(p + ((cB + 8) ^ x));
        return u.v;
    };

    f32x16 o0, o1;
    #pragma unroll
    for (int i = 0; i < 16; ++i) { o0[i] = 0.f; o1[i] = 0.f; }
    float l_run = 0.f;    // in-lane partial denominator for col t = l31

    // setprio brackets: interior brackets are LOAD-BEARING (R9/R11 failed
    // without them). Every MFMA stays bracketed; barriers/vmcnt untouched.
    auto SINIT = [&](int t, f32x16& s0, f32x16& s1) {
        if (t == nt - 1) {
            #pragma unroll
            for (int i = 0; i < 16; ++i) {
                const int sl = (i & 3) + 8 * (i >> 2) + 4 * hf;
                s0[i] = (t * 64 + sl      < cnt) ? 0.f : -30000.f;
                s1[i] = (t * 64 + sl + 32 < cnt) ? 0.f : -30000.f;
            }
        } else {
            #pragma unroll
            for (int i = 0; i < 16; ++i) { s0[i] = 0.f; s1[i] = 0.f; }
        }
    };

    auto QK = [&](int t, int buf, f32x16& s0, f32x16& s1) {
        SINIT(t, s0, s1);
        __builtin_amdgcn_s_setprio(1);
        #pragma unroll
        for (int kblk = 0; kblk < 4; ++kblk) {
            bf16x8 kf0 = LD8(Ks[buf], l31,      kblk * 32 + hf * 16);
            bf16x8 kf1 = LD8(Ks[buf], 32 + l31, kblk * 32 + hf * 16);
            s0 = __builtin_amdgcn_mfma_f32_32x32x16_bf16(kf0, qf[kblk], s0, 0, 0, 0);
            s1 = __builtin_amdgcn_mfma_f32_32x32x16_bf16(kf1, qf[kblk], s1, 0, 0, 0);
        }
        __builtin_amdgcn_s_setprio(0);
    };

    // fused: QK of tile B interleaved with exp2 of tile A's scores.
    auto QKxEXP = [&](int tB, int bufB, f32x16& sB0, f32x16& sB1,
                      f32x16& sA0, f32x16& sA1) {
        bf16x8 kB[8];
        #pragma unroll
        for (int kblk = 0; kblk < 4; ++kblk) {
            kB[2 * kblk]     = LD8(Ks[bufB], l31,      kblk * 32 + hf * 16);
            kB[2 * kblk + 1] = LD8(Ks[bufB], 32 + l31, kblk * 32 + hf * 16);
        }
        SINIT(tB, sB0, sB1);
        #pragma unroll
        for (int kblk = 0; kblk < 4; ++kblk) {
            __builtin_amdgcn_s_setprio(1);
            sB0 = __builtin_amdgcn_mfma_f32_32x32x16_bf16(kB[2 * kblk],     qf[kblk], sB0, 0, 0, 0);
            sB1 = __builtin_amdgcn_mfma_f32_32x32x16_bf16(kB[2 * kblk + 1], qf[kblk], sB1, 0, 0, 0);
            __builtin_amdgcn_s_setprio(0);
            if (kblk < 2) {
                #pragma unroll
                for (int j = 0; j < 8; ++j)
                    sA0[kblk * 8 + j] = __builtin_amdgcn_exp2f(sA0[kblk * 8 + j]);
            } else {
                #pragma unroll
                for (int j = 0; j < 8; ++j)
                    sA1[(kblk - 2) * 8 + j] = __builtin_amdgcn_exp2f(sA1[(kblk - 2) * 8 + j]);
            }
        }
    };

    // softmax FINISH: inputs already exp2'd; sums + cvt_pk/permlane pack.
    auto SMfin = [&](f32x16& s0, f32x16& s1, bf16x8* paw) {
        float t0 = 0.f, t1 = 0.f, t2 = 0.f, t3 = 0.f;
        #pragma unroll
        for (int i = 0; i < 4; ++i) {
            t0 += s0[i]      + s1[i];
            t1 += s0[4 + i]  + s1[4 + i];
            t2 += s0[8 + i]  + s1[8 + i];
            t3 += s0[12 + i] + s1[12 + i];
        }
        l_run += (t0 + t1) + (t2 + t3);

        #pragma unroll
        for (int ks2 = 0; ks2 < 4; ++ks2) {
            const int aX = (ks2 & 1) * 2;
            uint32_t X0, X1, Y0, Y1;
            #define CVTPK(dst, lo, hi) asm("v_cvt_pk_bf16_f32 %0, %1, %2" : "=v"(dst) : "v"(lo), "v"(hi))
            if (ks2 & 2) {
                CVTPK(X0, s1[4*aX + 0], s1[4*aX + 1]);
                CVTPK(X1, s1[4*aX + 2], s1[4*aX + 3]);
                CVTPK(Y0, s1[4*aX + 4], s1[4*aX + 5]);
                CVTPK(Y1, s1[4*aX + 6], s1[4*aX + 7]);
            } else {
                CVTPK(X0, s0[4*aX + 0], s0[4*aX + 1]);
                CVTPK(X1, s0[4*aX + 2], s0[4*aX + 3]);
                CVTPK(Y0, s0[4*aX + 4], s0[4*aX + 5]);
                CVTPK(Y1, s0[4*aX + 6], s0[4*aX + 7]);
            }
            #undef CVTPK
            asm("v_permlane32_swap_b32 %0, %1" : "+v"(X0), "+v"(Y0));
            asm("v_permlane32_swap_b32 %0, %1" : "+v"(X1), "+v"(Y1));
            union { u32x4 w; bf16x8 v; } u;
            u.w[0] = X0; u.w[1] = X1; u.w[2] = Y0; u.w[3] = Y1;
            paw[ks2] = u.v;
        }
    };

    // full softmax (exp2 + finish) for the tail path.
    auto SM = [&](f32x16& s0, f32x16& s1, bf16x8* paw) {
        #pragma unroll
        for (int i = 0; i < 16; ++i) {
            s0[i] = __builtin_amdgcn_exp2f(s0[i]);
            s1[i] = __builtin_amdgcn_exp2f(s1[i]);
        }
        SMfin(s0, s1, paw);
    };

    auto PV = [&](int buf, const bf16x8* paw) {
        __builtin_amdgcn_s_setprio(1);
        #pragma unroll
        for (int ks2 = 0; ks2 < 4; ++ks2) {
            bf16x8 vf0 = LD8(Vs[buf], l31,      ks2 * 32 + hf * 16);
            bf16x8 vf1 = LD8(Vs[buf], 32 + l31, ks2 * 32 + hf * 16);
            o0 = __builtin_amdgcn_mfma_f32_32x32x16_bf16(paw[ks2], vf0, o0, 0, 0, 0);
            o1 = __builtin_amdgcn_mfma_f32_32x32x16_bf16(paw[ks2], vf1, o1, 0, 0, 0);
        }
        __builtin_amdgcn_s_setprio(0);
    };

    // fused: PV of tile A interleaved with exp2 of tile B's scores.
    auto PVxEXP = [&](int bufA, const bf16x8* pawA,
                      f32x16& sB0, f32x16& sB1) {
        bf16x8 vA[8];
        #pragma unroll
        for (int ks2 = 0; ks2 < 4; ++ks2) {
            vA[2 * ks2]     = LD8(Vs[bufA], l31,      ks2 * 32 + hf * 16);
            vA[2 * ks2 + 1] = LD8(Vs[bufA], 32 + l31, ks2 * 32 + hf * 16);
        }
        #pragma unroll
        for (int ks2 = 0; ks2 < 4; ++ks2) {
            __builtin_amdgcn_s_setprio(1);
            o0 = __builtin_amdgcn_mfma_f32_32x32x16_bf16(pawA[ks2], vA[2 * ks2],     o0, 0, 0, 0);
            o1 = __builtin_amdgcn_mfma_f32_32x32x16_bf16(pawA[ks2], vA[2 * ks2 + 1], o1, 0, 0, 0);
            __builtin_amdgcn_s_setprio(0);
            if (ks2 < 2) {
                #pragma unroll
                for (int j = 0; j < 8; ++j)
                    sB0[ks2 * 8 + j] = __builtin_amdgcn_exp2f(sB0[ks2 * 8 + j]);
            } else {
                #pragma unroll
                for (int j = 0; j < 8; ++j)
                    sB1[(ks2 - 2) * 8 + j] = __builtin_amdgcn_exp2f(sB1[(ks2 - 2) * 8 + j]);
            }
        }
    };

    // ---- prologue staging
    STAGE(0, 0);
    if (1 < nt) STAGE(1, 1);

    int t = 0;
    for (; t + 1 < nt; t += 2) {
        const int n2 = (t + 2 < nt) ? 1 : 0;
        const int n3 = (t + 3 < nt) ? 1 : 0;
        if (n2) STAGE(t + 2, (t + 2) & 3);
        if (n3) STAGE(t + 3, (t + 3) & 3);
        if (n2 + n3 == 2)      asm volatile("s_waitcnt vmcnt(8)" ::: "memory");
        else if (n2 + n3 == 1) asm volatile("s_waitcnt vmcnt(4)" ::: "memory");
        else                   asm volatile("s_waitcnt vmcnt(0)" ::: "memory");
        __builtin_amdgcn_s_barrier();
        __builtin_amdgcn_sched_barrier(0);   // pin pair-start boundary

        f32x16 sA0, sA1, sB0, sB1;
        bf16x8 pawA[4], pawB[4];
        QK(t, t & 3, sA0, sA1);                         // bracketed
        QKxEXP(t + 1, (t + 1) & 3, sB0, sB1, sA0, sA1); // QK(B) ∥ exp2(A)
        SMfin(sA0, sA1, pawA);
        PVxEXP(t & 3, pawA, sB0, sB1);                  // PV(A) ∥ exp2(B)
        SMfin(sB0, sB1, pawB);
        PV((t + 1) & 3, pawB);                          // bracketed

        __builtin_amdgcn_sched_barrier(0);   // pin pair-end boundary
        __builtin_amdgcn_s_barrier();
    }
    if (t < nt) {   // odd-nt tail (tile already staged)
        asm volatile("s_waitcnt vmcnt(0)" ::: "memory");
        __builtin_amdgcn_s_barrier();
        __builtin_amdgcn_sched_barrier(0);
        f32x16 sA0, sA1;
        bf16x8 pawA[4];
        QK(t, t & 3, sA0, sA1);
        SM(sA0, sA1, pawA);
        PV(t & 3, pawA);
    }

    // ---- epilogue: combine halves of denom, normalize, store
    float lt = l_run + __shfl_xor(l_run, 32, 64);
    #pragma unroll
    for (int r = 0; r < 16; ++r) {
        const int t_r = (r & 3) + 8 * (r >> 2) + 4 * hf;
        const float den = __shfl(lt, t_r, 64);
        const float linv = den > 0.f ? 1.f / den : 0.f;
        float* op = out + ((size_t)(b * SQ + qrow0 + t_r) * NH + hq) * DD + l31;
        op[0]  = o0[r] * linv;
        op[32] = o1[r] * linv;
    }
}

extern "C" void kernel_launch(void* const* d_in, const int* in_sizes, int n_in,
                              void* d_out, int out_size, void* d_ws, size_t ws_size,
                              hipStream_t stream) {
    const float* q    = (const float*)d_in[0];
    const float* kv   = (const float*)d_in[1];
    const int*   mask = (const int*)d_in[2];
    float* out = (float*)d_out;

    gather_kernel<<<BB * HKV * MAXNT * 2, 256, 0, stream>>>(kv, mask, (char*)d_ws);
    fattn32p<<<BB * NH * (SQ / MTILE), 256, 0, stream>>>(q, (const char*)d_ws, out);
}

// Round 16
// 39.254 us; speedup vs baseline: 1.0107x; 1.0107x over previous
//
#include <hip/hip_runtime.h>
#include <hip/hip_bf16.h>
#include <stdint.h>

typedef __bf16 bf16_t;
typedef bf16_t bf16x8 __attribute__((ext_vector_type(8)));
typedef bf16_t bf16x4 __attribute__((ext_vector_type(4)));
typedef float f32x4 __attribute__((ext_vector_type(4)));
typedef float f32x16 __attribute__((ext_vector_type(16)));
typedef uint32_t u32x4 __attribute__((ext_vector_type(4)));
typedef int   i32x4 __attribute__((ext_vector_type(4)));

#define BB 2
#define SQ 2048
#define SK 2048
#define NH 16
#define HKV 4
#define DD 64
#define GQ 4
#define MTILE 128           // q rows per block (32 per wave, 4 waves)
#define NTILE 64
#define MAXNT 32

#define KTILE_BYTES 8192
#define CNT_OFF   ((size_t)0)
#define KC_OFF    ((size_t)4096)
#define VC_OFF    (KC_OFF + (size_t)BB * HKV * MAXNT * KTILE_BYTES)   // +2MB

// 128B rows, XOR swizzle at 8B granularity (R8-verified conflict-free).
__device__ __forceinline__ int swz8(int row, int colByte) {
    return row * 128 + (colByte ^ ((row & 15) << 3));
}

#define GLDS(g, l) __builtin_amdgcn_global_load_lds( \
    (const __attribute__((address_space(1))) void*)(g), \
    (__attribute__((address_space(3))) void*)(l), 16, 0, 0)

// ------------- pass 1: scan(mask) + gather + f32->bf16 + bake swizzle --------
// R14 config (measured best): fused parallel rescan, full-tile blocks.
__global__ __launch_bounds__(256)
void gather_kernel(const float* __restrict__ kv, const int* __restrict__ mask,
                   char* __restrict__ ws)
{
    __shared__ int wtot[4];
    __shared__ int cwin[NTILE];

    const int bid  = blockIdx.x;           // [b][hk][tile]
    const int tile = bid & 31;
    const int bh   = bid >> 5;
    const int hk   = bh & 3;
    const int b    = bh >> 2;
    const int tid  = threadIdx.x;
    const int lane = tid & 63;
    const int wid  = tid >> 6;

    int m[8], c = 0;
    {
        const int base = b * SK + tid * 8;
        i32x4 a0 = *(const i32x4*)&mask[base];
        i32x4 a1 = *(const i32x4*)&mask[base + 4];
        #pragma unroll
        for (int j = 0; j < 4; ++j) { m[j] = a0[j] ? 1 : 0; c += m[j]; }
        #pragma unroll
        for (int j = 0; j < 4; ++j) { m[4 + j] = a1[j] ? 1 : 0; c += m[4 + j]; }
    }
    int sc = c;
    #pragma unroll
    for (int off = 1; off < 64; off <<= 1) {
        int n = __shfl_up(sc, off, 64);
        if (lane >= off) sc += n;
    }
    if (lane == 63) wtot[wid] = sc;
    __syncthreads();
    int wbase = 0;
    #pragma unroll
    for (int w = 0; w < 4; ++w) if (w < wid) wbase += wtot[w];
    const int cnt = wtot[0] + wtot[1] + wtot[2] + wtot[3];

    if (hk == 0 && tile == 0 && tid == 0)
        ((int*)(ws + CNT_OFF))[b] = cnt;

    const int w0 = tile * NTILE;
    int pos = wbase + sc - c;              // exclusive prefix
    #pragma unroll
    for (int j = 0; j < 8; ++j)
        if (m[j]) {
            if (pos >= w0 && pos < w0 + NTILE) cwin[pos - w0] = tid * 8 + j;
            ++pos;
        }
    __syncthreads();

    const int nt = (cnt + 63) >> 6;
    if (tile >= nt) return;

    const int s4 = tid >> 4;               // 0..15
    const int d0 = (tid & 15) * 4;         // 0..60

    bf16_t* Kt = (bf16_t*)(ws + KC_OFF + (size_t)bid * KTILE_BYTES);
    bf16_t* Vt = (bf16_t*)(ws + VC_OFF + (size_t)bid * KTILE_BYTES);

    f32x4 kk4[4], vv4[4];
    #pragma unroll
    for (int p = 0; p < 4; ++p) {
        const int crow = w0 + s4 * 4 + p;
        if (crow < cnt) {
            const int s = cwin[s4 * 4 + p];
            const float* base = kv + (size_t)((b * SK + s) * 2) * (HKV * DD) + hk * DD + d0;
            kk4[p] = *(const f32x4*)base;
            vv4[p] = *(const f32x4*)(base + HKV * DD);
        } else {
            kk4[p] = (f32x4)(0.f);
            vv4[p] = (f32x4)(0.f);
        }
    }
    #pragma unroll
    for (int p = 0; p < 4; ++p) {
        bf16x4 kb;
        #pragma unroll
        for (int j = 0; j < 4; ++j) kb[j] = (bf16_t)kk4[p][j];
        *(bf16x4*)((char*)Kt + swz8(s4 * 4 + p, d0 * 2)) = kb;
    }
    #pragma unroll
    for (int j = 0; j < 4; ++j) {
        bf16x4 tv;
        #pragma unroll
        for (int p = 0; p < 4; ++p) tv[p] = (bf16_t)vv4[p][j];
        *(bf16x4*)((char*)Vt + swz8(d0 + j, s4 * 8)) = tv;   // V^T rows d
    }
}

// ------------- pass 2: pair-pipelined flash attn, ONE barrier per pair -------
__global__ __launch_bounds__(256, 2)
void fattn32p(const float* __restrict__ q, const char* __restrict__ ws,
              float* __restrict__ out)
{
    __shared__ __align__(16) bf16_t Ks[4][NTILE * 64];   // 32 KB
    __shared__ __align__(16) bf16_t Vs[4][DD * 64];      // 32 KB

    const int tid  = threadIdx.x;
    const int wid  = tid >> 6;
    const int lane = tid & 63;
    const int l31  = lane & 31;
    const int hf   = lane >> 5;

    // XCD-aware swizzle: 512 wgs, 8 XCDs, 64-wg chunks
    const int bid = (blockIdx.x & 7) * 64 + (blockIdx.x >> 3);
    const int qt  = bid & 15;
    const int bh  = bid >> 4;
    const int hq  = bh & 15;
    const int b   = bh >> 4;
    const int hk  = hq / GQ;

    const int cnt = ((const int*)(ws + CNT_OFF))[b];
    const int nt  = (cnt + 63) >> 6;

    const int qrow0 = qt * MTILE + wid * 32;
    const float SC = 0.18033688011112042f;   // 0.125 * log2(e)

    bf16x8 qf[4];
    {
        const float* qp = q + ((size_t)(b * SQ + qrow0 + l31) * NH + hq) * DD;
        #pragma unroll
        for (int kblk = 0; kblk < 4; ++kblk) {
            f32x4 v0 = *(const f32x4*)(qp + kblk * 16 + hf * 8);
            f32x4 v1 = *(const f32x4*)(qp + kblk * 16 + hf * 8 + 4);
            #pragma unroll
            for (int j = 0; j < 4; ++j) {
                qf[kblk][j]     = (bf16_t)(v0[j] * SC);
                qf[kblk][4 + j] = (bf16_t)(v1[j] * SC);
            }
        }
    }

    const char* kgb = ws + KC_OFF + (size_t)((b * HKV + hk) * MAXNT) * KTILE_BYTES;
    const char* vgb = ws + VC_OFF + (size_t)((b * HKV + hk) * MAXNT) * KTILE_BYTES;

    auto STAGE = [&](int t, int buf) {
        const char* ksrc = kgb + (size_t)t * KTILE_BYTES + wid * 2048 + lane * 16;
        const char* vsrc = vgb + (size_t)t * KTILE_BYTES + wid * 2048 + lane * 16;
        char* kdst = (char*)Ks[buf] + wid * 2048;
        char* vdst = (char*)Vs[buf] + wid * 2048;
        GLDS(ksrc, kdst);
        GLDS(ksrc + 1024, kdst + 1024);
        GLDS(vsrc, vdst);
        GLDS(vsrc + 1024, vdst + 1024);
    };

    // paired-b64 swizzled fragment read (bank-minimal, verified R8)
    auto LD8 = [&](const bf16_t* T, int row, int cB) -> bf16x8 {
        const char* p = (const char*)T + row * 128;
        const int x = (row & 15) << 3;
        union { bf16x4 h[2]; bf16x8 v; } u;
        u.h[0] = *(const bf16x4*)(p + (cB ^ x));
        u.h[1] = *(const bf16x4*)(p + ((cB + 8) ^ x));
        return u.v;
    };

    f32x16 o0, o1;
    #pragma unroll
    for (int i = 0; i < 16; ++i) { o0[i] = 0.f; o1[i] = 0.f; }
    float l_run = 0.f;    // in-lane partial denominator for col t = l31

    // setprio brackets: LOAD-BEARING (R9/R11 failed without them). Every
    // MFMA stays bracketed; the brackets are untouched in this round.
    auto SINIT = [&](int t, f32x16& s0, f32x16& s1) {
        if (t == nt - 1) {
            #pragma unroll
            for (int i = 0; i < 16; ++i) {
                const int sl = (i & 3) + 8 * (i >> 2) + 4 * hf;
                s0[i] = (t * 64 + sl      < cnt) ? 0.f : -30000.f;
                s1[i] = (t * 64 + sl + 32 < cnt) ? 0.f : -30000.f;
            }
        } else {
            #pragma unroll
            for (int i = 0; i < 16; ++i) { s0[i] = 0.f; s1[i] = 0.f; }
        }
    };

    auto QK = [&](int t, int buf, f32x16& s0, f32x16& s1) {
        SINIT(t, s0, s1);
        __builtin_amdgcn_s_setprio(1);
        #pragma unroll
        for (int kblk = 0; kblk < 4; ++kblk) {
            bf16x8 kf0 = LD8(Ks[buf], l31,      kblk * 32 + hf * 16);
            bf16x8 kf1 = LD8(Ks[buf], 32 + l31, kblk * 32 + hf * 16);
            s0 = __builtin_amdgcn_mfma_f32_32x32x16_bf16(kf0, qf[kblk], s0, 0, 0, 0);
            s1 = __builtin_amdgcn_mfma_f32_32x32x16_bf16(kf1, qf[kblk], s1, 0, 0, 0);
        }
        __builtin_amdgcn_s_setprio(0);
    };

    // fused: QK of tile B interleaved with exp2 of tile A's scores.
    auto QKxEXP = [&](int tB, int bufB, f32x16& sB0, f32x16& sB1,
                      f32x16& sA0, f32x16& sA1) {
        bf16x8 kB[8];
        #pragma unroll
        for (int kblk = 0; kblk < 4; ++kblk) {
            kB[2 * kblk]     = LD8(Ks[bufB], l31,      kblk * 32 + hf * 16);
            kB[2 * kblk + 1] = LD8(Ks[bufB], 32 + l31, kblk * 32 + hf * 16);
        }
        SINIT(tB, sB0, sB1);
        #pragma unroll
        for (int kblk = 0; kblk < 4; ++kblk) {
            __builtin_amdgcn_s_setprio(1);
            sB0 = __builtin_amdgcn_mfma_f32_32x32x16_bf16(kB[2 * kblk],     qf[kblk], sB0, 0, 0, 0);
            sB1 = __builtin_amdgcn_mfma_f32_32x32x16_bf16(kB[2 * kblk + 1], qf[kblk], sB1, 0, 0, 0);
            __builtin_amdgcn_s_setprio(0);
            if (kblk < 2) {
                #pragma unroll
                for (int j = 0; j < 8; ++j)
                    sA0[kblk * 8 + j] = __builtin_amdgcn_exp2f(sA0[kblk * 8 + j]);
            } else {
                #pragma unroll
                for (int j = 0; j < 8; ++j)
                    sA1[(kblk - 2) * 8 + j] = __builtin_amdgcn_exp2f(sA1[(kblk - 2) * 8 + j]);
            }
        }
    };

    // softmax FINISH: inputs already exp2'd; sums + cvt_pk/permlane pack.
    auto SMfin = [&](f32x16& s0, f32x16& s1, bf16x8* paw) {
        float t0 = 0.f, t1 = 0.f, t2 = 0.f, t3 = 0.f;
        #pragma unroll
        for (int i = 0; i < 4; ++i) {
            t0 += s0[i]      + s1[i];
            t1 += s0[4 + i]  + s1[4 + i];
            t2 += s0[8 + i]  + s1[8 + i];
            t3 += s0[12 + i] + s1[12 + i];
        }
        l_run += (t0 + t1) + (t2 + t3);

        #pragma unroll
        for (int ks2 = 0; ks2 < 4; ++ks2) {
            const int aX = (ks2 & 1) * 2;
            uint32_t X0, X1, Y0, Y1;
            #define CVTPK(dst, lo, hi) asm("v_cvt_pk_bf16_f32 %0, %1, %2" : "=v"(dst) : "v"(lo), "v"(hi))
            if (ks2 & 2) {
                CVTPK(X0, s1[4*aX + 0], s1[4*aX + 1]);
                CVTPK(X1, s1[4*aX + 2], s1[4*aX + 3]);
                CVTPK(Y0, s1[4*aX + 4], s1[4*aX + 5]);
                CVTPK(Y1, s1[4*aX + 6], s1[4*aX + 7]);
            } else {
                CVTPK(X0, s0[4*aX + 0], s0[4*aX + 1]);
                CVTPK(X1, s0[4*aX + 2], s0[4*aX + 3]);
                CVTPK(Y0, s0[4*aX + 4], s0[4*aX + 5]);
                CVTPK(Y1, s0[4*aX + 6], s0[4*aX + 7]);
            }
            #undef CVTPK
            asm("v_permlane32_swap_b32 %0, %1" : "+v"(X0), "+v"(Y0));
            asm("v_permlane32_swap_b32 %0, %1" : "+v"(X1), "+v"(Y1));
            union { u32x4 w; bf16x8 v; } u;
            u.w[0] = X0; u.w[1] = X1; u.w[2] = Y0; u.w[3] = Y1;
            paw[ks2] = u.v;
        }
    };

    // full softmax (exp2 + finish) for the tail path.
    auto SM = [&](f32x16& s0, f32x16& s1, bf16x8* paw) {
        #pragma unroll
        for (int i = 0; i < 16; ++i) {
            s0[i] = __builtin_amdgcn_exp2f(s0[i]);
            s1[i] = __builtin_amdgcn_exp2f(s1[i]);
        }
        SMfin(s0, s1, paw);
    };

    auto PV = [&](int buf, const bf16x8* paw) {
        __builtin_amdgcn_s_setprio(1);
        #pragma unroll
        for (int ks2 = 0; ks2 < 4; ++ks2) {
            bf16x8 vf0 = LD8(Vs[buf], l31,      ks2 * 32 + hf * 16);
            bf16x8 vf1 = LD8(Vs[buf], 32 + l31, ks2 * 32 + hf * 16);
            o0 = __builtin_amdgcn_mfma_f32_32x32x16_bf16(paw[ks2], vf0, o0, 0, 0, 0);
            o1 = __builtin_amdgcn_mfma_f32_32x32x16_bf16(paw[ks2], vf1, o1, 0, 0, 0);
        }
        __builtin_amdgcn_s_setprio(0);
    };

    // fused: PV of tile A interleaved with exp2 of tile B's scores.
    auto PVxEXP = [&](int bufA, const bf16x8* pawA,
                      f32x16& sB0, f32x16& sB1) {
        bf16x8 vA[8];
        #pragma unroll
        for (int ks2 = 0; ks2 < 4; ++ks2) {
            vA[2 * ks2]     = LD8(Vs[bufA], l31,      ks2 * 32 + hf * 16);
            vA[2 * ks2 + 1] = LD8(Vs[bufA], 32 + l31, ks2 * 32 + hf * 16);
        }
        #pragma unroll
        for (int ks2 = 0; ks2 < 4; ++ks2) {
            __builtin_amdgcn_s_setprio(1);
            o0 = __builtin_amdgcn_mfma_f32_32x32x16_bf16(pawA[ks2], vA[2 * ks2],     o0, 0, 0, 0);
            o1 = __builtin_amdgcn_mfma_f32_32x32x16_bf16(pawA[ks2], vA[2 * ks2 + 1], o1, 0, 0, 0);
            __builtin_amdgcn_s_setprio(0);
            if (ks2 < 2) {
                #pragma unroll
                for (int j = 0; j < 8; ++j)
                    sB0[ks2 * 8 + j] = __builtin_amdgcn_exp2f(sB0[ks2 * 8 + j]);
            } else {
                #pragma unroll
                for (int j = 0; j < 8; ++j)
                    sB1[(ks2 - 2) * 8 + j] = __builtin_amdgcn_exp2f(sB1[(ks2 - 2) * 8 + j]);
            }
        }
    };

    // ---- prologue staging
    STAGE(0, 0);
    if (1 < nt) STAGE(1, 1);

    // ONE barrier per pair (R16): STAGE moved AFTER the barrier. Safety:
    // iteration t reads bufs {t,t+1}&3 and writes bufs {t+2,t+3}&3 —
    // disjoint mod 4; the next write to buf t&3 is STAGE(t+4), issued only
    // after barrier(t+2), which all waves reach only after finishing this
    // pair's compute. vmcnt(0) at loop top is exact: only own tile-t/t+1
    // loads can still be outstanding (t+2/t+3 not yet issued).
    int t = 0;
    for (; t + 1 < nt; t += 2) {
        asm volatile("s_waitcnt vmcnt(0)" ::: "memory");
        __builtin_amdgcn_s_barrier();
        __builtin_amdgcn_sched_barrier(0);   // pin barrier boundary

        if (t + 2 < nt) STAGE(t + 2, (t + 2) & 3);
        if (t + 3 < nt) STAGE(t + 3, (t + 3) & 3);

        f32x16 sA0, sA1, sB0, sB1;
        bf16x8 pawA[4], pawB[4];
        QK(t, t & 3, sA0, sA1);                         // bracketed
        QKxEXP(t + 1, (t + 1) & 3, sB0, sB1, sA0, sA1); // QK(B) ∥ exp2(A)
        SMfin(sA0, sA1, pawA);
        PVxEXP(t & 3, pawA, sB0, sB1);                  // PV(A) ∥ exp2(B)
        SMfin(sB0, sB1, pawB);
        PV((t + 1) & 3, pawB);                          // bracketed
    }
    if (t < nt) {   // odd-nt tail (tile already staged)
        asm volatile("s_waitcnt vmcnt(0)" ::: "memory");
        __builtin_amdgcn_s_barrier();
        __builtin_amdgcn_sched_barrier(0);
        f32x16 sA0, sA1;
        bf16x8 pawA[4];
        QK(t, t & 3, sA0, sA1);
        SM(sA0, sA1, pawA);
        PV(t & 3, pawA);
    }

    // ---- epilogue: combine halves of denom, normalize, store
    float lt = l_run + __shfl_xor(l_run, 32, 64);
    #pragma unroll
    for (int r = 0; r < 16; ++r) {
        const int t_r = (r & 3) + 8 * (r >> 2) + 4 * hf;
        const float den = __shfl(lt, t_r, 64);
        const float linv = den > 0.f ? 1.f / den : 0.f;
        float* op = out + ((size_t)(b * SQ + qrow0 + t_r) * NH + hq) * DD + l31;
        op[0]  = o0[r] * linv;
        op[32] = o1[r] * linv;
    }
}

extern "C" void kernel_launch(void* const* d_in, const int* in_sizes, int n_in,
                              void* d_out, int out_size, void* d_ws, size_t ws_size,
                              hipStream_t stream) {
    const float* q    = (const float*)d_in[0];
    const float* kv   = (const float*)d_in[1];
    const int*   mask = (const int*)d_in[2];
    float* out = (float*)d_out;

    gather_kernel<<<BB * HKV * MAXNT, 256, 0, stream>>>(kv, mask, (char*)d_ws);
    fattn32p<<<BB * NH * (SQ / MTILE), 256, 0, stream>>>(q, (const char*)d_ws, out);
}

// Round 17
// 39.226 us; speedup vs baseline: 1.0114x; 1.0007x over previous
//
#include <hip/hip_runtime.h>
#include <hip/hip_bf16.h>
#include <stdint.h>

typedef __bf16 bf16_t;
typedef bf16_t bf16x8 __attribute__((ext_vector_type(8)));
typedef bf16_t bf16x4 __attribute__((ext_vector_type(4)));
typedef float f32x4 __attribute__((ext_vector_type(4)));
typedef float f32x16 __attribute__((ext_vector_type(16)));
typedef uint32_t u32x4 __attribute__((ext_vector_type(4)));
typedef int   i32x4 __attribute__((ext_vector_type(4)));

#define BB 2
#define SQ 2048
#define SK 2048
#define NH 16
#define HKV 4
#define DD 64
#define GQ 4
#define MTILE 128           // q rows per block (32 per wave, 4 waves)
#define NTILE 64
#define MAXNT 32

#define KTILE_BYTES 8192
#define CNT_OFF   ((size_t)0)
#define KC_OFF    ((size_t)4096)
#define VC_OFF    (KC_OFF + (size_t)BB * HKV * MAXNT * KTILE_BYTES)   // +2MB

// 128B rows, XOR swizzle at 8B granularity (R8-verified conflict-free).
__device__ __forceinline__ int swz8(int row, int colByte) {
    return row * 128 + (colByte ^ ((row & 15) << 3));
}

#define GLDS(g, l) __builtin_amdgcn_global_load_lds( \
    (const __attribute__((address_space(1))) void*)(g), \
    (__attribute__((address_space(3))) void*)(l), 16, 0, 0)

// ------------- pass 1: scan(mask) + gather + f32->bf16 + bake swizzle --------
// Fused parallel rescan (beats a serial scan stage, R12: +4.2 µs regression).
__global__ __launch_bounds__(256)
void gather_kernel(const float* __restrict__ kv, const int* __restrict__ mask,
                   char* __restrict__ ws)
{
    __shared__ int wtot[4];
    __shared__ int cwin[NTILE];

    const int bid  = blockIdx.x;           // [b][hk][tile]
    const int tile = bid & 31;
    const int bh   = bid >> 5;
    const int hk   = bh & 3;
    const int b    = bh >> 2;
    const int tid  = threadIdx.x;
    const int lane = tid & 63;
    const int wid  = tid >> 6;

    int m[8], c = 0;
    {
        const int base = b * SK + tid * 8;
        i32x4 a0 = *(const i32x4*)&mask[base];
        i32x4 a1 = *(const i32x4*)&mask[base + 4];
        #pragma unroll
        for (int j = 0; j < 4; ++j) { m[j] = a0[j] ? 1 : 0; c += m[j]; }
        #pragma unroll
        for (int j = 0; j < 4; ++j) { m[4 + j] = a1[j] ? 1 : 0; c += m[4 + j]; }
    }
    int sc = c;
    #pragma unroll
    for (int off = 1; off < 64; off <<= 1) {
        int n = __shfl_up(sc, off, 64);
        if (lane >= off) sc += n;
    }
    if (lane == 63) wtot[wid] = sc;
    __syncthreads();
    int wbase = 0;
    #pragma unroll
    for (int w = 0; w < 4; ++w) if (w < wid) wbase += wtot[w];
    const int cnt = wtot[0] + wtot[1] + wtot[2] + wtot[3];

    if (hk == 0 && tile == 0 && tid == 0)
        ((int*)(ws + CNT_OFF))[b] = cnt;

    const int w0 = tile * NTILE;
    int pos = wbase + sc - c;              // exclusive prefix
    #pragma unroll
    for (int j = 0; j < 8; ++j)
        if (m[j]) {
            if (pos >= w0 && pos < w0 + NTILE) cwin[pos - w0] = tid * 8 + j;
            ++pos;
        }
    __syncthreads();

    const int nt = (cnt + 63) >> 6;
    if (tile >= nt) return;

    const int s4 = tid >> 4;               // 0..15
    const int d0 = (tid & 15) * 4;         // 0..60

    bf16_t* Kt = (bf16_t*)(ws + KC_OFF + (size_t)bid * KTILE_BYTES);
    bf16_t* Vt = (bf16_t*)(ws + VC_OFF + (size_t)bid * KTILE_BYTES);

    f32x4 kk4[4], vv4[4];
    #pragma unroll
    for (int p = 0; p < 4; ++p) {
        const int crow = w0 + s4 * 4 + p;
        if (crow < cnt) {
            const int s = cwin[s4 * 4 + p];
            const float* base = kv + (size_t)((b * SK + s) * 2) * (HKV * DD) + hk * DD + d0;
            kk4[p] = *(const f32x4*)base;
            vv4[p] = *(const f32x4*)(base + HKV * DD);
        } else {
            kk4[p] = (f32x4)(0.f);
            vv4[p] = (f32x4)(0.f);
        }
    }
    #pragma unroll
    for (int p = 0; p < 4; ++p) {
        bf16x4 kb;
        #pragma unroll
        for (int j = 0; j < 4; ++j) kb[j] = (bf16_t)kk4[p][j];
        *(bf16x4*)((char*)Kt + swz8(s4 * 4 + p, d0 * 2)) = kb;
    }
    #pragma unroll
    for (int j = 0; j < 4; ++j) {
        bf16x4 tv;
        #pragma unroll
        for (int p = 0; p < 4; ++p) tv[p] = (bf16_t)vv4[p][j];
        *(bf16x4*)((char*)Vt + swz8(d0 + j, s4 * 8)) = tv;   // V^T rows d
    }
}

// ------------- pass 2: pair-pipelined flash attn, ONE barrier per pair -------
__global__ __launch_bounds__(256, 2)
void fattn32p(const float* __restrict__ q, const char* __restrict__ ws,
              float* __restrict__ out)
{
    __shared__ __align__(16) bf16_t Ks[4][NTILE * 64];   // 32 KB
    __shared__ __align__(16) bf16_t Vs[4][DD * 64];      // 32 KB

    const int tid  = threadIdx.x;
    const int wid  = tid >> 6;
    const int lane = tid & 63;
    const int l31  = lane & 31;
    const int hf   = lane >> 5;

    // XCD-aware swizzle: 512 wgs, 8 XCDs, 64-wg chunks
    const int bid = (blockIdx.x & 7) * 64 + (blockIdx.x >> 3);
    const int qt  = bid & 15;
    const int bh  = bid >> 4;
    const int hq  = bh & 15;
    const int b   = bh >> 4;
    const int hk  = hq / GQ;

    const int cnt = ((const int*)(ws + CNT_OFF))[b];
    const int nt  = (cnt + 63) >> 6;

    const int qrow0 = qt * MTILE + wid * 32;
    const float SC = 0.18033688011112042f;   // 0.125 * log2(e)

    bf16x8 qf[4];
    {
        const float* qp = q + ((size_t)(b * SQ + qrow0 + l31) * NH + hq) * DD;
        #pragma unroll
        for (int kblk = 0; kblk < 4; ++kblk) {
            f32x4 v0 = *(const f32x4*)(qp + kblk * 16 + hf * 8);
            f32x4 v1 = *(const f32x4*)(qp + kblk * 16 + hf * 8 + 4);
            #pragma unroll
            for (int j = 0; j < 4; ++j) {
                qf[kblk][j]     = (bf16_t)(v0[j] * SC);
                qf[kblk][4 + j] = (bf16_t)(v1[j] * SC);
            }
        }
    }

    const char* kgb = ws + KC_OFF + (size_t)((b * HKV + hk) * MAXNT) * KTILE_BYTES;
    const char* vgb = ws + VC_OFF + (size_t)((b * HKV + hk) * MAXNT) * KTILE_BYTES;

    auto STAGE = [&](int t, int buf) {
        const char* ksrc = kgb + (size_t)t * KTILE_BYTES + wid * 2048 + lane * 16;
        const char* vsrc = vgb + (size_t)t * KTILE_BYTES + wid * 2048 + lane * 16;
        char* kdst = (char*)Ks[buf] + wid * 2048;
        char* vdst = (char*)Vs[buf] + wid * 2048;
        GLDS(ksrc, kdst);
        GLDS(ksrc + 1024, kdst + 1024);
        GLDS(vsrc, vdst);
        GLDS(vsrc + 1024, vdst + 1024);
    };

    // paired-b64 swizzled fragment read (bank-minimal, verified R8)
    auto LD8 = [&](const bf16_t* T, int row, int cB) -> bf16x8 {
        const char* p = (const char*)T + row * 128;
        const int x = (row & 15) << 3;
        union { bf16x4 h[2]; bf16x8 v; } u;
        u.h[0] = *(const bf16x4*)(p + (cB ^ x));
        u.h[1] = *(const bf16x4*)(p + ((cB + 8) ^ x));
        return u.v;
    };

    f32x16 o0, o1;
    #pragma unroll
    for (int i = 0; i < 16; ++i) { o0[i] = 0.f; o1[i] = 0.f; }
    float l_run = 0.f;    // in-lane partial denominator for col t = l31

    // setprio brackets: LOAD-BEARING (R9/R11 failed without them). Every
    // MFMA stays bracketed.
    auto SINIT = [&](int t, f32x16& s0, f32x16& s1) {
        if (t == nt - 1) {
            #pragma unroll
            for (int i = 0; i < 16; ++i) {
                const int sl = (i & 3) + 8 * (i >> 2) + 4 * hf;
                s0[i] = (t * 64 + sl      < cnt) ? 0.f : -30000.f;
                s1[i] = (t * 64 + sl + 32 < cnt) ? 0.f : -30000.f;
            }
        } else {
            #pragma unroll
            for (int i = 0; i < 16; ++i) { s0[i] = 0.f; s1[i] = 0.f; }
        }
    };

    auto QK = [&](int t, int buf, f32x16& s0, f32x16& s1) {
        SINIT(t, s0, s1);
        __builtin_amdgcn_s_setprio(1);
        #pragma unroll
        for (int kblk = 0; kblk < 4; ++kblk) {
            bf16x8 kf0 = LD8(Ks[buf], l31,      kblk * 32 + hf * 16);
            bf16x8 kf1 = LD8(Ks[buf], 32 + l31, kblk * 32 + hf * 16);
            s0 = __builtin_amdgcn_mfma_f32_32x32x16_bf16(kf0, qf[kblk], s0, 0, 0, 0);
            s1 = __builtin_amdgcn_mfma_f32_32x32x16_bf16(kf1, qf[kblk], s1, 0, 0, 0);
        }
        __builtin_amdgcn_s_setprio(0);
    };

    // fused: QK of tile B interleaved with exp2 of tile A's scores.
    auto QKxEXP = [&](int tB, int bufB, f32x16& sB0, f32x16& sB1,
                      f32x16& sA0, f32x16& sA1) {
        bf16x8 kB[8];
        #pragma unroll
        for (int kblk = 0; kblk < 4; ++kblk) {
            kB[2 * kblk]     = LD8(Ks[bufB], l31,      kblk * 32 + hf * 16);
            kB[2 * kblk + 1] = LD8(Ks[bufB], 32 + l31, kblk * 32 + hf * 16);
        }
        SINIT(tB, sB0, sB1);
        #pragma unroll
        for (int kblk = 0; kblk < 4; ++kblk) {
            __builtin_amdgcn_s_setprio(1);
            sB0 = __builtin_amdgcn_mfma_f32_32x32x16_bf16(kB[2 * kblk],     qf[kblk], sB0, 0, 0, 0);
            sB1 = __builtin_amdgcn_mfma_f32_32x32x16_bf16(kB[2 * kblk + 1], qf[kblk], sB1, 0, 0, 0);
            __builtin_amdgcn_s_setprio(0);
            if (kblk < 2) {
                #pragma unroll
                for (int j = 0; j < 8; ++j)
                    sA0[kblk * 8 + j] = __builtin_amdgcn_exp2f(sA0[kblk * 8 + j]);
            } else {
                #pragma unroll
                for (int j = 0; j < 8; ++j)
                    sA1[(kblk - 2) * 8 + j] = __builtin_amdgcn_exp2f(sA1[(kblk - 2) * 8 + j]);
            }
        }
    };

    // softmax FINISH: inputs already exp2'd; sums + cvt_pk/permlane pack.
    auto SMfin = [&](f32x16& s0, f32x16& s1, bf16x8* paw) {
        float t0 = 0.f, t1 = 0.f, t2 = 0.f, t3 = 0.f;
        #pragma unroll
        for (int i = 0; i < 4; ++i) {
            t0 += s0[i]      + s1[i];
            t1 += s0[4 + i]  + s1[4 + i];
            t2 += s0[8 + i]  + s1[8 + i];
            t3 += s0[12 + i] + s1[12 + i];
        }
        l_run += (t0 + t1) + (t2 + t3);

        #pragma unroll
        for (int ks2 = 0; ks2 < 4; ++ks2) {
            const int aX = (ks2 & 1) * 2;
            uint32_t X0, X1, Y0, Y1;
            #define CVTPK(dst, lo, hi) asm("v_cvt_pk_bf16_f32 %0, %1, %2" : "=v"(dst) : "v"(lo), "v"(hi))
            if (ks2 & 2) {
                CVTPK(X0, s1[4*aX + 0], s1[4*aX + 1]);
                CVTPK(X1, s1[4*aX + 2], s1[4*aX + 3]);
                CVTPK(Y0, s1[4*aX + 4], s1[4*aX + 5]);
                CVTPK(Y1, s1[4*aX + 6], s1[4*aX + 7]);
            } else {
                CVTPK(X0, s0[4*aX + 0], s0[4*aX + 1]);
                CVTPK(X1, s0[4*aX + 2], s0[4*aX + 3]);
                CVTPK(Y0, s0[4*aX + 4], s0[4*aX + 5]);
                CVTPK(Y1, s0[4*aX + 6], s0[4*aX + 7]);
            }
            #undef CVTPK
            asm("v_permlane32_swap_b32 %0, %1" : "+v"(X0), "+v"(Y0));
            asm("v_permlane32_swap_b32 %0, %1" : "+v"(X1), "+v"(Y1));
            union { u32x4 w; bf16x8 v; } u;
            u.w[0] = X0; u.w[1] = X1; u.w[2] = Y0; u.w[3] = Y1;
            paw[ks2] = u.v;
        }
    };

    // full softmax (exp2 + finish) for the tail path.
    auto SM = [&](f32x16& s0, f32x16& s1, bf16x8* paw) {
        #pragma unroll
        for (int i = 0; i < 16; ++i) {
            s0[i] = __builtin_amdgcn_exp2f(s0[i]);
            s1[i] = __builtin_amdgcn_exp2f(s1[i]);
        }
        SMfin(s0, s1, paw);
    };

    auto PV = [&](int buf, const bf16x8* paw) {
        __builtin_amdgcn_s_setprio(1);
        #pragma unroll
        for (int ks2 = 0; ks2 < 4; ++ks2) {
            bf16x8 vf0 = LD8(Vs[buf], l31,      ks2 * 32 + hf * 16);
            bf16x8 vf1 = LD8(Vs[buf], 32 + l31, ks2 * 32 + hf * 16);
            o0 = __builtin_amdgcn_mfma_f32_32x32x16_bf16(paw[ks2], vf0, o0, 0, 0, 0);
            o1 = __builtin_amdgcn_mfma_f32_32x32x16_bf16(paw[ks2], vf1, o1, 0, 0, 0);
        }
        __builtin_amdgcn_s_setprio(0);
    };

    // fused: PV of tile A interleaved with exp2 of tile B's scores.
    auto PVxEXP = [&](int bufA, const bf16x8* pawA,
                      f32x16& sB0, f32x16& sB1) {
        bf16x8 vA[8];
        #pragma unroll
        for (int ks2 = 0; ks2 < 4; ++ks2) {
            vA[2 * ks2]     = LD8(Vs[bufA], l31,      ks2 * 32 + hf * 16);
            vA[2 * ks2 + 1] = LD8(Vs[bufA], 32 + l31, ks2 * 32 + hf * 16);
        }
        #pragma unroll
        for (int ks2 = 0; ks2 < 4; ++ks2) {
            __builtin_amdgcn_s_setprio(1);
            o0 = __builtin_amdgcn_mfma_f32_32x32x16_bf16(pawA[ks2], vA[2 * ks2],     o0, 0, 0, 0);
            o1 = __builtin_amdgcn_mfma_f32_32x32x16_bf16(pawA[ks2], vA[2 * ks2 + 1], o1, 0, 0, 0);
            __builtin_amdgcn_s_setprio(0);
            if (ks2 < 2) {
                #pragma unroll
                for (int j = 0; j < 8; ++j)
                    sB0[ks2 * 8 + j] = __builtin_amdgcn_exp2f(sB0[ks2 * 8 + j]);
            } else {
                #pragma unroll
                for (int j = 0; j < 8; ++j)
                    sB1[(ks2 - 2) * 8 + j] = __builtin_amdgcn_exp2f(sB1[(ks2 - 2) * 8 + j]);
            }
        }
    };

    // ---- prologue staging
    STAGE(0, 0);
    if (1 < nt) STAGE(1, 1);

    // ONE barrier per pair: STAGE after the barrier; bufs disjoint mod 4;
    // vmcnt(0) at loop top is exact (only own tile-t/t+1 loads outstanding).
    int t = 0;
    for (; t + 1 < nt; t += 2) {
        asm volatile("s_waitcnt vmcnt(0)" ::: "memory");
        __builtin_amdgcn_s_barrier();
        __builtin_amdgcn_sched_barrier(0);   // pin barrier boundary

        if (t + 2 < nt) STAGE(t + 2, (t + 2) & 3);
        if (t + 3 < nt) STAGE(t + 3, (t + 3) & 3);

        f32x16 sA0, sA1, sB0, sB1;
        bf16x8 pawA[4], pawB[4];
        QK(t, t & 3, sA0, sA1);                         // bracketed
        QKxEXP(t + 1, (t + 1) & 3, sB0, sB1, sA0, sA1); // QK(B) ∥ exp2(A)
        SMfin(sA0, sA1, pawA);
        PVxEXP(t & 3, pawA, sB0, sB1);                  // PV(A) ∥ exp2(B)
        SMfin(sB0, sB1, pawB);
        PV((t + 1) & 3, pawB);                          // bracketed
    }
    if (t < nt) {   // odd-nt tail (tile already staged)
        asm volatile("s_waitcnt vmcnt(0)" ::: "memory");
        __builtin_amdgcn_s_barrier();
        __builtin_amdgcn_sched_barrier(0);
        f32x16 sA0, sA1;
        bf16x8 pawA[4];
        QK(t, t & 3, sA0, sA1);
        SM(sA0, sA1, pawA);
        PV(t & 3, pawA);
    }

    // ---- epilogue: combine halves of denom, normalize, store
    float lt = l_run + __shfl_xor(l_run, 32, 64);
    #pragma unroll
    for (int r = 0; r < 16; ++r) {
        const int t_r = (r & 3) + 8 * (r >> 2) + 4 * hf;
        const float den = __shfl(lt, t_r, 64);
        const float linv = den > 0.f ? 1.f / den : 0.f;
        float* op = out + ((size_t)(b * SQ + qrow0 + t_r) * NH + hq) * DD + l31;
        op[0]  = o0[r] * linv;
        op[32] = o1[r] * linv;
    }
}

extern "C" void kernel_launch(void* const* d_in, const int* in_sizes, int n_in,
                              void* d_out, int out_size, void* d_ws, size_t ws_size,
                              hipStream_t stream) {
    const float* q    = (const float*)d_in[0];
    const float* kv   = (const float*)d_in[1];
    const int*   mask = (const int*)d_in[2];
    float* out = (float*)d_out;

    gather_kernel<<<BB * HKV * MAXNT, 256, 0, stream>>>(kv, mask, (char*)d_ws);
    fattn32p<<<BB * NH * (SQ / MTILE), 256, 0, stream>>>(q, (const char*)d_ws, out);
}